// Round 6
// baseline (298.919 us; speedup 1.0000x reference)
//
#include <hip/hip_runtime.h>
#include <hip/hip_bf16.h>
#include <hip/hip_fp16.h>
#include <stdint.h>

#define B_ 8
#define K_ 2048
#define D_ 1024
#define NC 64
#define TC (K_ / NC)   // 32 timesteps per chunk

typedef float v4f __attribute__((ext_vector_type(4)));
typedef short v8s __attribute__((ext_vector_type(8)));
typedef unsigned short v8u __attribute__((ext_vector_type(8)));

__device__ __forceinline__ unsigned short f2bf(float f) {
    __hip_bfloat16 h = __float2bfloat16(f);
    return *reinterpret_cast<unsigned short*>(&h);
}
__device__ __forceinline__ float bf2f(unsigned short u) {
    uint32_t v = (uint32_t)u << 16;
    float f;
    __builtin_memcpy(&f, &v, 4);
    return f;
}
__device__ __forceinline__ float h2f(unsigned short u) {
    __half h;
    __builtin_memcpy(&h, &u, 2);
    return __half2float(h);
}

__device__ __forceinline__ void async_ld16(const void* g, void* l) {
    __builtin_amdgcn_global_load_lds(
        (__attribute__((address_space(1))) void*)(void*)g,
        (__attribute__((address_space(3))) void*)l,
        16, 0, 0);
}

// ------- fused converters: blocks [0,4096) transpose x -> xT bf16 [B][D][K],
//         blocks [4096,8192) convert W -> Wb bf16. One launch instead of two. -------
__global__ void conv_fused(const float* __restrict__ x, const float* __restrict__ W,
                           unsigned short* __restrict__ xT, unsigned short* __restrict__ Wb) {
    const int blk = blockIdx.x;
    const int tid = threadIdx.x;
    if (blk >= 4096) {
        int i = ((blk - 4096) * 256 + tid) * 4;
        float4 v = *(const float4*)(W + i);
        ushort4 o;
        o.x = f2bf(v.x); o.y = f2bf(v.y); o.z = f2bf(v.z); o.w = f2bf(v.w);
        *(ushort4*)(Wb + i) = o;
        return;
    }
    const int k0 = (blk & 31) * 64, d0 = ((blk >> 5) & 15) * 64, bb = blk >> 9;
    __shared__ unsigned short tile[64][68];   // pad 68 to break bank alignment
    const int tx = tid & 15, ty = tid >> 4;
    const float* xp = x + (size_t)bb * K_ * D_;
#pragma unroll
    for (int r = 0; r < 4; r++) {
        int row = ty + r * 16;
        float4 v = *(const float4*)(xp + (size_t)(k0 + row) * D_ + d0 + tx * 4);
        tile[row][tx * 4 + 0] = f2bf(v.x);
        tile[row][tx * 4 + 1] = f2bf(v.y);
        tile[row][tx * 4 + 2] = f2bf(v.z);
        tile[row][tx * 4 + 3] = f2bf(v.w);
    }
    __syncthreads();
    unsigned short* op = xT + (size_t)bb * D_ * K_;
#pragma unroll
    for (int r = 0; r < 4; r++) {
        int dcol = ty + r * 16;
        ushort4 u;
        u.x = tile[tx * 4 + 0][dcol];
        u.y = tile[tx * 4 + 1][dcol];
        u.z = tile[tx * 4 + 2][dcol];
        u.w = tile[tx * 4 + 3][dcol];
        *(ushort4*)(op + (size_t)(d0 + dcol) * K_ + k0 + tx * 4) = u;
    }
}

// ---------------- GEMM + bias + sigmoid -> lamT[b][d][t] fp16 ----------------
// Main loop = proven R3 config: 128x128 tile, 4 waves @ 64x64, BK=64 as two BK=32
// sub-buffers, lane-linear global_load_lds (R2: permuted lanes cost 13%; R4: bigger
// tiles regress 43% — occupancy/barrier bound, stay at 128^2).
// Epilogue: acc r=0..3 are 4 CONSECUTIVE t -> pack 4 fp16 into one 8B store to the
// t-contiguous lamT layout (16 stores/thread; R5's 64 short-stores cost +15us).
__launch_bounds__(256)
__global__ void gemm_sig(const unsigned short* __restrict__ Wb,
                         const unsigned short* __restrict__ xT,
                         const float* __restrict__ bias,
                         unsigned short* __restrict__ lamT) {
    const int tM = blockIdx.x, tN = blockIdx.y, bb = blockIdx.z;
    __shared__ unsigned short As[2][128 * 32];
    __shared__ unsigned short Bs[2][128 * 32];
    const int tid = threadIdx.x;
    const int w = tid >> 6;
    const int lane = tid & 63;
    const int wm = w >> 1, wn = w & 1;
    const int quad = lane >> 4;
    const int l16 = lane & 15;

    v4f acc[4][4];
#pragma unroll
    for (int i = 0; i < 4; i++)
#pragma unroll
        for (int j = 0; j < 4; j++) acc[i][j] = (v4f)0.f;

    const unsigned short* Ag = Wb + (size_t)(tM * 128) * K_;
    const unsigned short* Bg = xT + (size_t)bb * D_ * K_ + (size_t)(tN * 128) * K_;

    const int srow = lane >> 2;          // 0..15
    const int schunk = (lane & 3) * 8;   // lane-linear source (coalescing-friendly)

    for (int k0 = 0; k0 < K_; k0 += 64) {
#pragma unroll
        for (int h = 0; h < 2; h++) {
#pragma unroll
            for (int q = 0; q < 2; q++) {
                int rb = (q * 4 + w) * 16;
                async_ld16(Ag + (size_t)(rb + srow) * K_ + k0 + h * 32 + schunk, &As[h][rb * 32]);
                async_ld16(Bg + (size_t)(rb + srow) * K_ + k0 + h * 32 + schunk, &Bs[h][rb * 32]);
            }
        }
        __syncthreads();
#pragma unroll
        for (int h = 0; h < 2; h++) {
            v8s af[4], bfr[4];
#pragma unroll
            for (int i = 0; i < 4; i++)
                af[i] = *(const v8s*)(&As[h][(wm * 64 + i * 16 + l16) * 32 + quad * 8]);
#pragma unroll
            for (int j = 0; j < 4; j++)
                bfr[j] = *(const v8s*)(&Bs[h][(wn * 64 + j * 16 + l16) * 32 + quad * 8]);
#pragma unroll
            for (int i = 0; i < 4; i++)
#pragma unroll
                for (int j = 0; j < 4; j++)
                    acc[i][j] = __builtin_amdgcn_mfma_f32_16x16x32_bf16(af[i], bfr[j], acc[i][j], 0, 0, 0);
        }
        __syncthreads();
    }

    unsigned short* lt = lamT + (size_t)bb * D_ * K_;
#pragma unroll
    for (int i = 0; i < 4; i++) {
        int rowb = tM * 128 + wm * 64 + i * 16 + quad * 4;   // t base (4-aligned)
        float4 bv = *(const float4*)(bias + rowb);
#pragma unroll
        for (int j = 0; j < 4; j++) {
            int col = tN * 128 + wn * 64 + j * 16 + l16;     // d
            float s0 = 1.f / (1.f + __expf(-(acc[i][j][0] + bv.x)));
            float s1 = 1.f / (1.f + __expf(-(acc[i][j][1] + bv.y)));
            float s2 = 1.f / (1.f + __expf(-(acc[i][j][2] + bv.z)));
            float s3 = 1.f / (1.f + __expf(-(acc[i][j][3] + bv.w)));
            union { __half2 h[2]; uint2 u; } pk;
            pk.h[0] = __float22half2_rn(make_float2(s0, s1));
            pk.h[1] = __float22half2_rn(make_float2(s2, s3));
            *(uint2*)(lt + (size_t)col * K_ + rowb) = pk.u;  // 8B, t-contiguous
        }
    }
}

// -------- scan pass 1: per-(b,chunk,d) affine composition (A,U).
// lamT fp16 and xT bf16 are both [b][d][t] -> per-thread CONTIGUOUS b128 loads. --------
__global__ void scan_pass1(const unsigned short* __restrict__ lamT,
                           const unsigned short* __restrict__ xT,
                           float* __restrict__ Ac, float* __restrict__ Uc) {
    int id = blockIdx.x * 256 + threadIdx.x;   // B*NC*D = 524288
    int d = id & (D_ - 1);
    int c = (id >> 10) & (NC - 1);
    int bb = id >> 16;
    size_t base = ((size_t)bb * D_ + d) * K_ + (size_t)c * TC;
    const unsigned short* lp = lamT + base;
    const unsigned short* xp = xT + base;
    float A = 1.f, U = 0.f;
#pragma unroll
    for (int u = 0; u < TC / 8; u++) {
        v8u lv = *(const v8u*)(lp + u * 8);
        v8u xv = *(const v8u*)(xp + u * 8);
#pragma unroll
        for (int e = 0; e < 8; e++) {
            float l = h2f(lv[e]);
            float xf = bf2f(xv[e]);
            A *= l;
            U = l * U + (1.f - l) * xf;
        }
    }
    int oi = (bb * NC + c) * D_ + d;
    Ac[oi] = A;
    Uc[oi] = U;
}

// -------- scan pass 2+3 merged: chunk-entry state from L2-hot Ac/Uc (c is
// block-uniform), then replay chunk; out stores are lane-coalesced [t][d]. --------
__global__ void scan_pass23(const unsigned short* __restrict__ lamT,
                            const unsigned short* __restrict__ xT,
                            const float* __restrict__ Ac, const float* __restrict__ Uc,
                            float* __restrict__ out) {
    int id = blockIdx.x * 256 + threadIdx.x;   // 524288
    int d = id & (D_ - 1);
    int c = (id >> 10) & (NC - 1);
    int bb = id >> 16;
    float s = 0.f;
    for (int cc = 0; cc < c; cc++) {
        int ai = (bb * NC + cc) * D_ + d;
        s = Ac[ai] * s + Uc[ai];
    }
    size_t base = ((size_t)bb * D_ + d) * K_ + (size_t)c * TC;
    const unsigned short* lp = lamT + base;
    const unsigned short* xp = xT + base;
    float* op = out + ((size_t)bb * K_ + (size_t)c * TC) * D_ + d;
#pragma unroll
    for (int u = 0; u < TC / 8; u++) {
        v8u lv = *(const v8u*)(lp + u * 8);
        v8u xv = *(const v8u*)(xp + u * 8);
#pragma unroll
        for (int e = 0; e < 8; e++) {
            float l = h2f(lv[e]);
            float xf = bf2f(xv[e]);
            s = l * s + (1.f - l) * xf;
            op[(size_t)(u * 8 + e) * D_] = s;
        }
    }
}

extern "C" void kernel_launch(void* const* d_in, const int* in_sizes, int n_in,
                              void* d_out, int out_size, void* d_ws, size_t ws_size,
                              hipStream_t stream) {
    const float* x    = (const float*)d_in[0];
    const float* W    = (const float*)d_in[1];
    const float* bias = (const float*)d_in[2];
    float* out = (float*)d_out;
    char* ws = (char*)d_ws;

    const size_t MB = 1024 * 1024;
    unsigned short* xT   = (unsigned short*)ws;               // 32 MiB [B][D][K] bf16 (= x transposed; k==t so scans reuse it)
    unsigned short* Wb   = (unsigned short*)(ws + 32 * MB);   // 8 MiB  [K][K] bf16
    // Ac/Uc overlay Wb (dead after gemm); lamT at 40MB. Total footprint 72 MiB
    // (R5's WRITE_SIZE=32MB proves ws_size >= 72 MiB on this harness).
    float* Ac = (float*)(ws + 32 * MB);                       // 2 MiB
    float* Uc = (float*)(ws + 34 * MB);                       // 2 MiB
    unsigned short* lamT = (unsigned short*)(ws + 40 * MB);   // 32 MiB [B][D][K(=t)] fp16

    conv_fused<<<dim3(8192), 256, 0, stream>>>(x, W, xT, Wb);
    gemm_sig<<<dim3(K_ / 128, D_ / 128, B_), 256, 0, stream>>>(Wb, xT, bias, lamT);
    scan_pass1<<<dim3(B_ * NC * D_ / 256), 256, 0, stream>>>(lamT, xT, Ac, Uc);
    scan_pass23<<<dim3(B_ * NC * D_ / 256), 256, 0, stream>>>(lamT, xT, Ac, Uc, out);
}